// Round 4
// baseline (330.835 us; speedup 1.0000x reference)
//
#include <hip/hip_runtime.h>
#include <math.h>

// ---------------------------------------------------------------------------
// MambaAnglePredictor: fc -> in_proj -> conv+silu -> chunked SSM scan (SSD)
//   -> gate+RMSNorm -> out_proj -> MLP -> mean -> angle
// Round 4: mgemm rewritten barrier-free — both MFMA operands loaded straight
//          from global in fragment order (B pre-transformed, L2-resident).
// ---------------------------------------------------------------------------

#define BDIM 4
#define LDIM 4096
#define BL (BDIM*LDIM)      // 16384 tokens
#define DM 192
#define DI 384
#define DS 64
#define NH 8
#define HD 48
#define QC 64               // chunk length
#define NC (LDIM/QC)        // 64 chunks
#define BH (BDIM*NH)        // 32

// workspace offsets (floats). total = 39,059,584 floats = 156.2 MB (unchanged)
#define OFF_H    0u          // h_hi/h_lo bf16 (3,145,728 fl total); later h2 fp32
#define OFF_Z    3145728u    // z fp32 16384*384
#define OFF_XBC  9437184u    // xbc fp32 -> T -> y_hi/y_lo bf16
#define OFF_T    OFF_XBC
#define OFF_XS   17825792u   // 32*4096*48
#define OFF_BM   24117248u   // 16384*64
#define OFF_CM   25165824u   // 16384*64
#define OFF_DT   26214400u   // 32*4096
#define OFF_LAC  26345472u   // 2048*64
#define OFF_SP   26476544u   // Wt_in early / Sp mid / Wt_out late
#define OFF_Y    32768000u   // 16384*384 fp32
#define OFF_MACC 39059456u   // 4*32

typedef unsigned short ushort_t;
typedef __attribute__((ext_vector_type(8))) short bf16x8;
typedef __attribute__((ext_vector_type(4))) float f32x4;

__device__ __forceinline__ float sigmoidf_(float x){ return 1.0f/(1.0f+__expf(-x)); }
__device__ __forceinline__ ushort_t f2bf(float x){
  unsigned int u = __float_as_uint(x);
  u += 0x7fffu + ((u>>16)&1u);
  return (ushort_t)(u>>16);
}
__device__ __forceinline__ float bf2f(ushort_t h){
  return __uint_as_float(((unsigned int)h)<<16);
}

// ------------------ K1: h = x@Wfc + bfc, emitted as bf16 hi/lo --------------
__global__ void k_fc(const float* __restrict__ x, const float* __restrict__ Wfc,
                     const float* __restrict__ bfc,
                     ushort_t* __restrict__ hhi, ushort_t* __restrict__ hlo){
  int bl = blockIdx.x; int d = threadIdx.x;
  float4 xv = *(const float4*)(x + bl*4);
  float acc = bfc[d];
  acc = fmaf(xv.x, Wfc[d], acc);
  acc = fmaf(xv.y, Wfc[192+d], acc);
  acc = fmaf(xv.z, Wfc[384+d], acc);
  acc = fmaf(xv.w, Wfc[576+d], acc);
  ushort_t hi = f2bf(acc);
  size_t idx = (size_t)bl*192 + d;
  hhi[idx] = hi;
  hlo[idx] = f2bf(acc - bf2f(hi));
}

// ------- weight pre-transform: W(KxN fp32) -> hi/lo bf16 [K/32][Npad][32] ----
template<int K, int N, int Npad>
__global__ void k_wt(const float* __restrict__ W,
                     ushort_t* __restrict__ Wh, ushort_t* __restrict__ Wl){
  int kt = blockIdx.x;
  int n = blockIdx.y*256 + threadIdx.x;
  if (n >= Npad) return;
  for (int k=0;k<32;k++){
    float v = (n < N) ? W[(size_t)(kt*32+k)*N + n] : 0.f;
    ushort_t hi = f2bf(v);
    size_t o = ((size_t)kt*Npad + n)*32 + k;
    Wh[o] = hi;
    Wl[o] = f2bf(v - bf2f(hi));
  }
}

// ------------- MFMA split-bf16 GEMM, barrier-free, no LDS -------------------
// A: M x K bf16 hi/lo row-major (fragment = 16B contiguous row segment).
// B: pre-transformed [K/32][Npad][32] hi/lo (fragment = 16B contiguous).
// 128 x BN tile, 4 waves: wave covers 64(m) x BN/2(n).
// MODE 0: out[m*N+n] fp32. MODE 1: in_proj epilogue (z / xbc / softplus dt).
template<int K, int N, int Npad, int BN, int MODE>
__global__ __launch_bounds__(256) void k_mgemm(
    const ushort_t* __restrict__ Ah, const ushort_t* __restrict__ Al,
    const ushort_t* __restrict__ Bh, const ushort_t* __restrict__ Bl,
    float* __restrict__ out, float* __restrict__ zbuf, float* __restrict__ xbcb,
    float* __restrict__ dtbuf, const float* __restrict__ dt_bias){
  const int NF = BN/32;                 // 16-wide n-frags per wave
  int tid = threadIdx.x;
  int m0 = blockIdx.x*128, n0 = blockIdx.y*BN;
  int w = tid>>6, lane = tid&63;
  int wm = (w>>1)*64, wn = (w&1)*(BN/2);
  int l15 = lane&15, quad = lane>>4;

  f32x4 acc[4][NF];
  #pragma unroll
  for (int i=0;i<4;i++)
    #pragma unroll
    for (int j=0;j<NF;j++) acc[i][j] = (f32x4)(0.f);

  // per-lane base pointers
  const ushort_t* aH = Ah + (size_t)(m0+wm+l15)*K + quad*8;
  const ushort_t* aL = Al + (size_t)(m0+wm+l15)*K + quad*8;
  const ushort_t* bH = Bh + ((size_t)(n0+wn+l15))*32 + quad*8;
  const ushort_t* bL = Bl + ((size_t)(n0+wn+l15))*32 + quad*8;

  for (int k0=0;k0<K;k0+=32){
    bf16x8 fBh[NF], fBl[NF];
    size_t bko = (size_t)(k0>>5)*Npad*32;
    #pragma unroll
    for (int ni=0;ni<NF;ni++){
      fBh[ni] = *(const bf16x8*)(bH + bko + ni*16*32);
      fBl[ni] = *(const bf16x8*)(bL + bko + ni*16*32);
    }
    bf16x8 fAh[4], fAl[4];
    #pragma unroll
    for (int mi=0;mi<4;mi++){
      fAh[mi] = *(const bf16x8*)(aH + (size_t)mi*16*K + k0);
      fAl[mi] = *(const bf16x8*)(aL + (size_t)mi*16*K + k0);
    }
    #pragma unroll
    for (int mi=0;mi<4;mi++)
      #pragma unroll
      for (int ni=0;ni<NF;ni++){
        acc[mi][ni] = __builtin_amdgcn_mfma_f32_16x16x32_bf16(fAh[mi], fBh[ni], acc[mi][ni], 0,0,0);
        acc[mi][ni] = __builtin_amdgcn_mfma_f32_16x16x32_bf16(fAh[mi], fBl[ni], acc[mi][ni], 0,0,0);
        acc[mi][ni] = __builtin_amdgcn_mfma_f32_16x16x32_bf16(fAl[mi], fBh[ni], acc[mi][ni], 0,0,0);
      }
  }
  // epilogue: C/D layout col = lane&15, row = quad*4 + reg
  #pragma unroll
  for (int mi=0;mi<4;mi++)
    #pragma unroll
    for (int ni=0;ni<NF;ni++)
      #pragma unroll
      for (int r=0;r<4;r++){
        int m = m0 + wm + mi*16 + quad*4 + r;
        int n = n0 + wn + ni*16 + l15;
        float v = acc[mi][ni][r];
        if (MODE==0){
          if (n < N) out[(size_t)m*N + n] = v;
        } else {
          if (n < 384){
            zbuf[(size_t)m*384 + n] = v;
          } else if (n < 896){
            xbcb[(size_t)m*512 + (n-384)] = v;
          } else if (n < 904){
            int hh = n - 896;
            float xx = v + dt_bias[hh];
            float dtv = (xx > 20.f) ? xx : log1pf(__expf(xx));
            int b = m >> 12, l = m & 4095;
            dtbuf[(size_t)(b*8+hh)*4096 + l] = dtv;
          }
        }
      }
}

// ------------------- K3: depthwise causal conv(4) + silu -------------------
__global__ void k_conv(const float* __restrict__ xbc, const float* __restrict__ conv_w,
                       const float* __restrict__ conv_b, float* __restrict__ xs,
                       float* __restrict__ Bm, float* __restrict__ Cm){
  int idx = blockIdx.x*256 + threadIdx.x;
  int bl = idx >> 9, c = idx & 511;
  int l = bl & 4095, b = bl >> 12;
  float acc = conv_b[c];
  #pragma unroll
  for (int k=0;k<4;k++){
    int ll = l - 3 + k;
    if (ll >= 0) acc = fmaf(conv_w[k*512+c], xbc[(size_t)(bl-3+k)*512 + c], acc);
  }
  float v = acc * sigmoidf_(acc);
  if (c < 384){
    int hh = c / 48, p = c - hh*48;
    xs[(size_t)((b*8+hh)*4096 + l)*48 + p] = v;
  } else if (c < 448){
    Bm[(size_t)bl*64 + (c-384)] = v;
  } else {
    Cm[(size_t)bl*64 + (c-448)] = v;
  }
}

// ----- K4 phase1: per-chunk cumlog(dA), chunk state T_k = sum w_s B_s x_s^T -----
__global__ __launch_bounds__(256) void k_phase1(
    const float* __restrict__ dtbuf, const float* __restrict__ Bm,
    const float* __restrict__ xs, const float* __restrict__ A_log,
    float* __restrict__ T, float* __restrict__ lac){
  __shared__ float sdt[64], sla[64], sw[64];
  __shared__ __align__(16) float sBW[64][64];
  __shared__ __align__(16) float sX[64][48];
  int tid = threadIdx.x, blk = blockIdx.x;
  int bh = blk >> 6, k = blk & 63;
  int b = bh >> 3, hh = bh & 7;
  int t0 = k*64;
  if (tid < 64) sdt[tid] = dtbuf[(size_t)bh*4096 + t0 + tid];
  __syncthreads();
  if (tid == 0){
    float eA = __expf(A_log[hh]);
    float cum = 0.f;
    for (int i=0;i<64;i++){ cum -= sdt[i]*eA; sla[i] = cum; }
  }
  __syncthreads();
  if (tid < 64){
    sw[tid] = __expf(sla[63]-sla[tid])*sdt[tid];
    lac[(size_t)blk*64 + tid] = sla[tid];
  }
  __syncthreads();
  {
    int s = tid>>2, n0 = (tid&3)*16;
    float wsc = sw[s];
    const float* src = Bm + (size_t)(b*4096 + t0 + s)*64 + n0;
    #pragma unroll
    for (int q=0;q<4;q++){
      float4 v = *(const float4*)(src + q*4);
      v.x*=wsc; v.y*=wsc; v.z*=wsc; v.w*=wsc;
      *(float4*)&sBW[s][n0+q*4] = v;
    }
    int p0 = (tid&3)*12;
    const float* xsrc = xs + (size_t)(bh*4096 + t0 + s)*48 + p0;
    #pragma unroll
    for (int q=0;q<3;q++) *(float4*)&sX[s][p0+q*4] = *(const float4*)(xsrc + q*4);
  }
  __syncthreads();
  if (tid < 192){
    int n0 = (tid/12)*4, p0 = (tid%12)*4;
    float acc[4][4];
    #pragma unroll
    for (int i=0;i<4;i++)
      #pragma unroll
      for (int j=0;j<4;j++) acc[i][j]=0.f;
    for (int s=0;s<64;s++){
      float bw[4], xv[4];
      *(float4*)bw = *(float4*)&sBW[s][n0];
      *(float4*)xv = *(float4*)&sX[s][p0];
      #pragma unroll
      for (int i=0;i<4;i++)
        #pragma unroll
        for (int j=0;j<4;j++) acc[i][j] = fmaf(bw[i], xv[j], acc[i][j]);
    }
    float* dst = T + (size_t)blk*3072;
    #pragma unroll
    for (int i=0;i<4;i++){
      float4 o; o.x=acc[i][0]; o.y=acc[i][1]; o.z=acc[i][2]; o.w=acc[i][3];
      *(float4*)(dst + (n0+i)*48 + p0) = o;
    }
  }
}

// ----- K5 phase2: sequential chunk-carry; stores S_prev per chunk -----
__global__ __launch_bounds__(384) void k_phase2(
    const float* __restrict__ T, const float* __restrict__ lac, float* __restrict__ Sp){
  __shared__ float ssc[64];
  int tid = threadIdx.x, bh = blockIdx.x, sl = blockIdx.y;
  if (tid < 64) ssc[tid] = __expf(lac[(size_t)(bh*64+tid)*64 + 63]);
  __syncthreads();
  size_t base = (size_t)bh*64*3072 + sl*384 + tid;
  float s = 0.f;
  float nv = T[base];
  for (int k=0;k<64;k++){
    float c = nv;
    if (k<63) nv = T[base + (size_t)(k+1)*3072];
    Sp[base + (size_t)k*3072] = s;
    s = fmaf(ssc[k], s, c);
  }
}

// ----- K6 phase3: Y = (L o C B^T) X + diag(exp(la)) C S_prev + D*x -----
__global__ __launch_bounds__(256, 3) void k_phase3(
    const float* __restrict__ dtbuf, const float* __restrict__ lac,
    const float* __restrict__ Bm, const float* __restrict__ Cm,
    const float* __restrict__ xs, const float* __restrict__ Sp,
    const float* __restrict__ Dparam, float* __restrict__ y){
  __shared__ __align__(16) float sBt[64][68];  // B^T [n][s] -> X [s][p]
  __shared__ __align__(16) float sCt[64][68];  // C^T [n][i]
  __shared__ __align__(16) float sSG[64][68];  // Sp [n][p] -> GM^T [s][i]
  __shared__ float sdt[64], sla[64];
  int tid = threadIdx.x, blk = blockIdx.x;
  int bh = blk>>6, k = blk&63, b = bh>>3, hh = bh&7, t0 = k*64;

  int rs = tid>>2, c0 = (tid&3)*12;
  float4 xpre0, xpre1, xpre2;
  {
    const float* xsrc = xs + (size_t)(bh*4096+t0+rs)*48 + c0;
    xpre0 = *(const float4*)(xsrc);
    xpre1 = *(const float4*)(xsrc+4);
    xpre2 = *(const float4*)(xsrc+8);
  }
  if (tid < 64){
    sdt[tid] = dtbuf[(size_t)bh*4096 + t0 + tid];
    sla[tid] = lac[(size_t)blk*64 + tid];
  }
  {
    const float* ssrc = Sp + (size_t)blk*3072 + rs*48 + c0;
    *(float4*)&sSG[rs][c0]   = *(const float4*)(ssrc);
    *(float4*)&sSG[rs][c0+4] = *(const float4*)(ssrc+4);
    *(float4*)&sSG[rs][c0+8] = *(const float4*)(ssrc+8);
  }
  {
    int s = tid>>2, n0 = (tid&3)*16;
    const float* bsrc = Bm + (size_t)(b*4096+t0+s)*64 + n0;
    const float* csrc = Cm + (size_t)(b*4096+t0+s)*64 + n0;
    #pragma unroll
    for (int q=0;q<4;q++){
      float4 bv = *(const float4*)(bsrc + q*4);
      float4 cv = *(const float4*)(csrc + q*4);
      sBt[n0+q*4+0][s]=bv.x; sBt[n0+q*4+1][s]=bv.y; sBt[n0+q*4+2][s]=bv.z; sBt[n0+q*4+3][s]=bv.w;
      sCt[n0+q*4+0][s]=cv.x; sCt[n0+q*4+1][s]=cv.y; sCt[n0+q*4+2][s]=cv.z; sCt[n0+q*4+3][s]=cv.w;
    }
  }
  __syncthreads();

  int i0p = (tid/12)*4, p0 = (tid%12)*4;
  float acc[4][4];
  #pragma unroll
  for (int i=0;i<4;i++)
    #pragma unroll
    for (int j=0;j<4;j++) acc[i][j]=0.f;
  if (tid < 192){
    #pragma unroll 4
    for (int n=0;n<64;n++){
      float cv[4], sp[4];
      *(float4*)cv = *(float4*)&sCt[n][i0p];
      *(float4*)sp = *(float4*)&sSG[n][p0];
      #pragma unroll
      for (int ii=0;ii<4;ii++)
        #pragma unroll
        for (int j=0;j<4;j++) acc[ii][j] = fmaf(cv[ii], sp[j], acc[ii][j]);
    }
  }
  int ig = (tid>>4)*4, sg = (tid&15)*4;
  float gm[4][4];
  #pragma unroll
  for (int i=0;i<4;i++)
    #pragma unroll
    for (int j=0;j<4;j++) gm[i][j]=0.f;
  if (sg <= ig+3){
    #pragma unroll 4
    for (int n=0;n<64;n++){
      float cv[4], bv[4];
      *(float4*)cv = *(float4*)&sCt[n][ig];
      *(float4*)bv = *(float4*)&sBt[n][sg];
      #pragma unroll
      for (int ii=0;ii<4;ii++)
        #pragma unroll
        for (int ss=0;ss<4;ss++) gm[ii][ss] = fmaf(cv[ii], bv[ss], gm[ii][ss]);
    }
    #pragma unroll
    for (int ii=0;ii<4;ii++)
      #pragma unroll
      for (int ss=0;ss<4;ss++){
        int i = ig+ii, s = sg+ss;
        gm[ii][ss] = (s<=i) ? gm[ii][ss]*__expf(sla[i]-sla[s])*sdt[s] : 0.f;
      }
  }
  __syncthreads();

  #pragma unroll
  for (int ss=0;ss<4;ss++){
    float4 o; o.x=gm[0][ss]; o.y=gm[1][ss]; o.z=gm[2][ss]; o.w=gm[3][ss];
    *(float4*)&sSG[sg+ss][ig] = o;
  }
  *(float4*)&sBt[rs][c0]   = xpre0;
  *(float4*)&sBt[rs][c0+4] = xpre1;
  *(float4*)&sBt[rs][c0+8] = xpre2;
  if (tid < 192){
    #pragma unroll
    for (int ii=0;ii<4;ii++){
      float ci = __expf(sla[i0p+ii]);
      #pragma unroll
      for (int j=0;j<4;j++) acc[ii][j] *= ci;
    }
  }
  __syncthreads();

  if (tid < 192){
    for (int s0=0; s0<=i0p; s0+=4){
      #pragma unroll
      for (int q=0;q<4;q++){
        float gv[4], xv[4];
        *(float4*)gv = *(float4*)&sSG[s0+q][i0p];
        *(float4*)xv = *(float4*)&sBt[s0+q][p0];
        #pragma unroll
        for (int ii=0;ii<4;ii++)
          #pragma unroll
          for (int j=0;j<4;j++) acc[ii][j] = fmaf(gv[ii], xv[j], acc[ii][j]);
      }
    }
    float Dh = Dparam[hh];
    #pragma unroll
    for (int ii=0;ii<4;ii++){
      int i = i0p+ii;
      float4 xd = *(float4*)&sBt[i][p0];
      float4 o;
      o.x = acc[ii][0] + Dh*xd.x;
      o.y = acc[ii][1] + Dh*xd.y;
      o.z = acc[ii][2] + Dh*xd.z;
      o.w = acc[ii][3] + Dh*xd.w;
      *(float4*)(y + (size_t)(b*4096+t0+i)*384 + hh*48 + p0) = o;
    }
  }
}

// ----- K7a: v = y*silu(z); RMSNorm*norm_w; emit bf16 hi/lo for out_proj -----
__global__ __launch_bounds__(384) void k_gate(
    const float* __restrict__ zbuf, const float* __restrict__ norm_w,
    const float* __restrict__ y,
    ushort_t* __restrict__ yhi, ushort_t* __restrict__ ylo){
  __shared__ float sred[6];
  __shared__ float srms;
  int bl = blockIdx.x, tid = threadIdx.x;
  float yv = y[(size_t)bl*384 + tid];
  float zv = zbuf[(size_t)bl*384 + tid];
  float g = yv * (zv * sigmoidf_(zv));
  float ss = g*g;
  #pragma unroll
  for (int off=32; off>0; off>>=1) ss += __shfl_xor(ss, off);
  if ((tid&63)==0) sred[tid>>6] = ss;
  __syncthreads();
  if (tid==0){
    float t=0.f;
    #pragma unroll
    for (int i=0;i<6;i++) t += sred[i];
    srms = rsqrtf(t*(1.f/384.f) + 1e-5f);
  }
  __syncthreads();
  float g2 = g * srms * norm_w[tid];
  ushort_t hi = f2bf(g2);
  size_t idx = (size_t)bl*384 + tid;
  yhi[idx] = hi;
  ylo[idx] = f2bf(g2 - bf2f(hi));
}

// ----- K8: MLP (192->32 relu, 32->32 relu) + partial mean accumulation -----
__global__ __launch_bounds__(256) void k_mlp(
    const float* __restrict__ h2, const float* __restrict__ W1, const float* __restrict__ b1,
    const float* __restrict__ W2, const float* __restrict__ b2, float* __restrict__ macc){
  __shared__ __align__(16) float sh2[32][192];
  __shared__ __align__(16) float sW1[192][32];
  __shared__ __align__(16) float sm1[32][32];
  __shared__ __align__(16) float sW2[32][32];
  __shared__ __align__(16) float sm2[32][32];
  int tid = threadIdx.x;
  int tok0 = blockIdx.x*32;
  int b = tok0 >> 12;
  #pragma unroll
  for (int r=0;r<6;r++){
    int e4 = tid + r*256;
    int row = e4/48, c4 = (e4%48)*4;
    *(float4*)&sh2[row][c4] = *(const float4*)(h2 + (size_t)(tok0+row)*192 + c4);
  }
  #pragma unroll
  for (int r=0;r<6;r++){
    int e4 = tid + r*256;
    int row = e4>>3, c4 = (e4&7)*4;
    *(float4*)&sW1[row][c4] = *(const float4*)(W1 + row*32 + c4);
  }
  {
    int row = tid>>3, c4 = (tid&7)*4;
    *(float4*)&sW2[row][c4] = *(const float4*)(W2 + row*32 + c4);
  }
  __syncthreads();
  {
    int tok = tid>>3, j0 = (tid&7)*4;
    float a0[4];
    #pragma unroll
    for (int j=0;j<4;j++) a0[j] = b1[j0+j];
    for (int kk=0;kk<192;kk++){
      float a = sh2[tok][kk];
      float w[4]; *(float4*)w = *(float4*)&sW1[kk][j0];
      #pragma unroll
      for (int j=0;j<4;j++) a0[j] = fmaf(a, w[j], a0[j]);
    }
    float4 o;
    o.x=fmaxf(a0[0],0.f); o.y=fmaxf(a0[1],0.f); o.z=fmaxf(a0[2],0.f); o.w=fmaxf(a0[3],0.f);
    *(float4*)&sm1[tok][j0] = o;
  }
  __syncthreads();
  {
    int tok = tid>>3, j0 = (tid&7)*4;
    float a0[4];
    #pragma unroll
    for (int j=0;j<4;j++) a0[j] = b2[j0+j];
    #pragma unroll
    for (int kk=0;kk<32;kk++){
      float a = sm1[tok][kk];
      float w[4]; *(float4*)w = *(float4*)&sW2[kk][j0];
      #pragma unroll
      for (int j=0;j<4;j++) a0[j] = fmaf(a, w[j], a0[j]);
    }
    float4 o;
    o.x=fmaxf(a0[0],0.f); o.y=fmaxf(a0[1],0.f); o.z=fmaxf(a0[2],0.f); o.w=fmaxf(a0[3],0.f);
    *(float4*)&sm2[tok][j0] = o;
  }
  __syncthreads();
  if (tid < 32){
    float t = 0.f;
    #pragma unroll
    for (int tok=0;tok<32;tok++) t += sm2[tok][tid];
    atomicAdd(&macc[b*32 + tid], t);
  }
}

// ----- K9: angle[b] = mean_m @ Wo + bo -----
__global__ void k_final(const float* __restrict__ macc, const float* __restrict__ Wo,
                        const float* __restrict__ bo, float* __restrict__ out){
  int tid = threadIdx.x;
  if (tid < 4){
    float acc = bo[0];
    #pragma unroll
    for (int j=0;j<32;j++) acc = fmaf(macc[tid*32+j]*(1.f/4096.f), Wo[j], acc);
    out[tid] = acc;
  }
}

// ---------------------------------------------------------------------------
extern "C" void kernel_launch(void* const* d_in, const int* in_sizes, int n_in,
                              void* d_out, int out_size, void* d_ws, size_t ws_size,
                              hipStream_t stream){
  const float* x      = (const float*)d_in[0];
  const float* Wfc    = (const float*)d_in[1];
  const float* bfc    = (const float*)d_in[2];
  const float* W_in   = (const float*)d_in[3];
  const float* conv_w = (const float*)d_in[4];
  const float* conv_b = (const float*)d_in[5];
  const float* dt_bias= (const float*)d_in[6];
  const float* A_log  = (const float*)d_in[7];
  const float* Dparam = (const float*)d_in[8];
  const float* norm_w = (const float*)d_in[9];
  const float* W_out  = (const float*)d_in[10];
  const float* W1     = (const float*)d_in[11];
  const float* b1     = (const float*)d_in[12];
  const float* W2     = (const float*)d_in[13];
  const float* b2     = (const float*)d_in[14];
  const float* Wo     = (const float*)d_in[15];
  const float* bo     = (const float*)d_in[16];
  float* ws  = (float*)d_ws;
  float* out = (float*)d_out;

  ushort_t* hhi = (ushort_t*)(ws + OFF_H);
  ushort_t* hlo = (ushort_t*)(ws + OFF_H) + 3145728u;      // 16384*192
  float* h2   = ws + OFF_H;                                 // reused after in_proj
  float* zb   = ws + OFF_Z;
  float* xbc  = ws + OFF_XBC;
  float* Tb   = ws + OFF_T;
  ushort_t* yhi = (ushort_t*)(ws + OFF_T);                  // reused after phase2
  ushort_t* ylo = (ushort_t*)(ws + OFF_T) + 6291456u;       // 16384*384
  float* xsb  = ws + OFF_XS;
  float* Bmb  = ws + OFF_BM;
  float* Cmb  = ws + OFF_CM;
  float* dtb  = ws + OFF_DT;
  float* lacb = ws + OFF_LAC;
  float* Spb  = ws + OFF_SP;
  ushort_t* wtih = (ushort_t*)(ws + OFF_SP);                // W_in transform (early)
  ushort_t* wtil = (ushort_t*)(ws + OFF_SP) + 196608u;      // 6*1024*32
  ushort_t* wtoh = (ushort_t*)(ws + OFF_SP);                // W_out transform (late)
  ushort_t* wtol = (ushort_t*)(ws + OFF_SP) + 73728u;       // 12*192*32
  float* yb   = ws + OFF_Y;
  float* macc = ws + OFF_MACC;

  hipMemsetAsync((void*)macc, 0, 128*sizeof(float), stream);

  k_wt<192,904,1024><<<dim3(6,4), dim3(256), 0, stream>>>(W_in, wtih, wtil);
  k_fc<<<dim3(BL), dim3(192), 0, stream>>>(x, Wfc, bfc, hhi, hlo);
  k_mgemm<192,904,1024,128,1><<<dim3(128,8), dim3(256), 0, stream>>>(
      hhi, hlo, wtih, wtil, nullptr, zb, xbc, dtb, dt_bias);
  k_conv<<<dim3(BL*512/256), dim3(256), 0, stream>>>(xbc, conv_w, conv_b, xsb, Bmb, Cmb);
  k_phase1<<<dim3(BH*NC), dim3(256), 0, stream>>>(dtb, Bmb, xsb, A_log, Tb, lacb);
  k_phase2<<<dim3(BH,8), dim3(384), 0, stream>>>(Tb, lacb, Spb);
  k_phase3<<<dim3(BH*NC), dim3(256), 0, stream>>>(dtb, lacb, Bmb, Cmb, xsb, Spb, Dparam, yb);
  k_gate<<<dim3(BL), dim3(384), 0, stream>>>(zb, norm_w, yb, yhi, ylo);
  k_wt<384,192,192><<<dim3(12,1), dim3(256), 0, stream>>>(W_out, wtoh, wtol);
  k_mgemm<384,192,192,96,0><<<dim3(128,2), dim3(256), 0, stream>>>(
      yhi, ylo, wtoh, wtol, h2, nullptr, nullptr, nullptr, nullptr);
  k_mlp<<<dim3(BL/32), dim3(256), 0, stream>>>(h2, W1, b1, W2, b2, macc);
  k_final<<<dim3(1), dim3(64), 0, stream>>>(macc, Wo, bo, out);
}

// Round 5
// 249.967 us; speedup vs baseline: 1.3235x; 1.3235x over previous
//
#include <hip/hip_runtime.h>
#include <math.h>

// ---------------------------------------------------------------------------
// MambaAnglePredictor — Round 5: algebraic collapse.
//   zxbcdt = x @ (Wfc@W_in) + bfc@W_in   (K=4 — no big GEMM at all)
//   conv fused with in_proj (xBC recomputed per token, never materialized)
//   z recomputed at gate time; out_proj folded into MLP (Weff2 = W_out@W1)
// Pipeline: prep -> ipc(conv) -> phase1 -> phase2 -> phase3 -> gate -> mlp2 -> final
// ---------------------------------------------------------------------------

#define BDIM 4
#define LDIM 4096
#define BL (BDIM*LDIM)      // 16384 tokens
#define QC 64               // chunk length
#define NC (LDIM/QC)        // 64 chunks
#define BH (BDIM*NH)        // 32
#define NH 8

// workspace offsets (floats)
#define OFF_W    0u          // Weff_in 4x904 @0, beff @4096, Weff2 @8192 (12288)
#define OFF_Z    3145728u    // yn (normalized y) fp32 16384*384
#define OFF_T    9437184u    // T 2048*3072
#define OFF_XS   17825792u   // 32*4096*48
#define OFF_BM   24117248u   // 16384*64
#define OFF_CM   25165824u   // 16384*64
#define OFF_DT   26214400u   // 32*4096
#define OFF_LAC  26345472u   // 2048*64
#define OFF_SP   26476544u   // 2048*64*3072
#define OFF_Y    32768000u   // 16384*384 fp32
#define OFF_MACC 39059456u   // 4*32

__device__ __forceinline__ float sigmoidf_(float x){ return 1.0f/(1.0f+__expf(-x)); }

// ----- prep1: Weff_in[r][n] = sum_d Wfc[r][d] W_in[d][n]; beff[n] = bfc@W_in -----
__global__ void k_prep1(const float* __restrict__ Wfc, const float* __restrict__ bfc,
                        const float* __restrict__ W_in,
                        float* __restrict__ Weff, float* __restrict__ beff){
  int n = blockIdx.x*256 + threadIdx.x;
  if (n >= 904) return;
  float a0=0.f,a1=0.f,a2=0.f,a3=0.f,ab=0.f;
  for (int d=0; d<192; d++){
    float w = W_in[(size_t)d*904 + n];
    a0 = fmaf(Wfc[d], w, a0);
    a1 = fmaf(Wfc[192+d], w, a1);
    a2 = fmaf(Wfc[384+d], w, a2);
    a3 = fmaf(Wfc[576+d], w, a3);
    ab = fmaf(bfc[d], w, ab);
  }
  Weff[n] = a0; Weff[904+n] = a1; Weff[1808+n] = a2; Weff[2712+n] = a3;
  beff[n] = ab;
}

// ----- prep2: Weff2[i][j] = sum_d W_out[i][d] W1[d][j] (384x32) -----
__global__ void k_prep2(const float* __restrict__ W_out, const float* __restrict__ W1,
                        float* __restrict__ Weff2){
  int g = blockIdx.x*256 + threadIdx.x;   // 12288
  int i = g>>5, j = g&31;
  float a = 0.f;
  for (int d=0; d<192; d++) a = fmaf(W_out[(size_t)i*192+d], W1[d*32+j], a);
  Weff2[g] = a;
}

// ----- ipc: fused in_proj(xBC cols)+conv+silu+dt. One block per token. -----
__global__ __launch_bounds__(256) void k_ipc(
    const float* __restrict__ x, const float* __restrict__ Weff,
    const float* __restrict__ beff, const float* __restrict__ conv_w,
    const float* __restrict__ conv_b, const float* __restrict__ dt_bias,
    float* __restrict__ xs, float* __restrict__ Bm, float* __restrict__ Cm,
    float* __restrict__ dtb){
  __shared__ float sx[4][4];            // [k][r] for tokens l-3+k
  int bl = blockIdx.x, tid = threadIdx.x;
  int l = bl & 4095, b = bl >> 12;
  if (tid < 16){
    int k = tid>>2, r = tid&3;
    int ll = l-3+k;
    sx[k][r] = (ll>=0) ? x[(size_t)(b*4096+ll)*4 + r] : 0.f;
  }
  __syncthreads();
  // dt: cols 896..903
  if (tid < 8){
    float raw = beff[896+tid];
    #pragma unroll
    for (int r=0;r<4;r++) raw = fmaf(sx[3][r], Weff[r*904+896+tid], raw);
    float xx = raw + dt_bias[tid];
    float dtv = (xx > 20.f) ? xx : log1pf(__expf(xx));
    dtb[(size_t)(b*8+tid)*4096 + l] = dtv;
  }
  #pragma unroll
  for (int half=0; half<2; half++){
    int c = tid + half*256;             // xBC col 0..511 -> Weff col 384+c
    float w0 = Weff[384+c];
    float w1 = Weff[904+384+c];
    float w2 = Weff[1808+384+c];
    float w3 = Weff[2712+384+c];
    float bb = beff[384+c];
    float acc = conv_b[c];
    #pragma unroll
    for (int k=0;k<4;k++){
      int ll = l-3+k;
      float xv = bb;
      xv = fmaf(sx[k][0], w0, xv);
      xv = fmaf(sx[k][1], w1, xv);
      xv = fmaf(sx[k][2], w2, xv);
      xv = fmaf(sx[k][3], w3, xv);
      if (ll < 0) xv = 0.f;             // zero-pad is on xBC, pre-conv
      acc = fmaf(conv_w[k*512+c], xv, acc);
    }
    float v = acc * sigmoidf_(acc);
    if (c < 384){
      int hh = c / 48, p = c - hh*48;
      xs[(size_t)((b*8+hh)*4096 + l)*48 + p] = v;
    } else if (c < 448){
      Bm[(size_t)bl*64 + (c-384)] = v;
    } else {
      Cm[(size_t)bl*64 + (c-448)] = v;
    }
  }
}

// ----- phase1: per-chunk cumlog(dA), chunk state T_k = sum w_s B_s x_s^T -----
__global__ __launch_bounds__(256) void k_phase1(
    const float* __restrict__ dtbuf, const float* __restrict__ Bm,
    const float* __restrict__ xs, const float* __restrict__ A_log,
    float* __restrict__ T, float* __restrict__ lac){
  __shared__ float sdt[64], sla[64], sw[64];
  __shared__ __align__(16) float sBW[64][64];
  __shared__ __align__(16) float sX[64][48];
  int tid = threadIdx.x, blk = blockIdx.x;
  int bh = blk >> 6, k = blk & 63;
  int b = bh >> 3, hh = bh & 7;
  int t0 = k*64;
  if (tid < 64) sdt[tid] = dtbuf[(size_t)bh*4096 + t0 + tid];
  __syncthreads();
  if (tid == 0){
    float eA = __expf(A_log[hh]);
    float cum = 0.f;
    for (int i=0;i<64;i++){ cum -= sdt[i]*eA; sla[i] = cum; }
  }
  __syncthreads();
  if (tid < 64){
    sw[tid] = __expf(sla[63]-sla[tid])*sdt[tid];
    lac[(size_t)blk*64 + tid] = sla[tid];
  }
  __syncthreads();
  {
    int s = tid>>2, n0 = (tid&3)*16;
    float wsc = sw[s];
    const float* src = Bm + (size_t)(b*4096 + t0 + s)*64 + n0;
    #pragma unroll
    for (int q=0;q<4;q++){
      float4 v = *(const float4*)(src + q*4);
      v.x*=wsc; v.y*=wsc; v.z*=wsc; v.w*=wsc;
      *(float4*)&sBW[s][n0+q*4] = v;
    }
    int p0 = (tid&3)*12;
    const float* xsrc = xs + (size_t)(bh*4096 + t0 + s)*48 + p0;
    #pragma unroll
    for (int q=0;q<3;q++) *(float4*)&sX[s][p0+q*4] = *(const float4*)(xsrc + q*4);
  }
  __syncthreads();
  if (tid < 192){
    int n0 = (tid/12)*4, p0 = (tid%12)*4;
    float acc[4][4];
    #pragma unroll
    for (int i=0;i<4;i++)
      #pragma unroll
      for (int j=0;j<4;j++) acc[i][j]=0.f;
    for (int s=0;s<64;s++){
      float bw[4], xv[4];
      *(float4*)bw = *(float4*)&sBW[s][n0];
      *(float4*)xv = *(float4*)&sX[s][p0];
      #pragma unroll
      for (int i=0;i<4;i++)
        #pragma unroll
        for (int j=0;j<4;j++) acc[i][j] = fmaf(bw[i], xv[j], acc[i][j]);
    }
    float* dst = T + (size_t)blk*3072;
    #pragma unroll
    for (int i=0;i<4;i++){
      float4 o; o.x=acc[i][0]; o.y=acc[i][1]; o.z=acc[i][2]; o.w=acc[i][3];
      *(float4*)(dst + (n0+i)*48 + p0) = o;
    }
  }
}

// ----- phase2: sequential chunk-carry; stores S_prev per chunk -----
__global__ __launch_bounds__(384) void k_phase2(
    const float* __restrict__ T, const float* __restrict__ lac, float* __restrict__ Sp){
  __shared__ float ssc[64];
  int tid = threadIdx.x, bh = blockIdx.x, sl = blockIdx.y;
  if (tid < 64) ssc[tid] = __expf(lac[(size_t)(bh*64+tid)*64 + 63]);
  __syncthreads();
  size_t base = (size_t)bh*64*3072 + sl*384 + tid;
  float s = 0.f;
  float nv = T[base];
  for (int k=0;k<64;k++){
    float c = nv;
    if (k<63) nv = T[base + (size_t)(k+1)*3072];
    Sp[base + (size_t)k*3072] = s;
    s = fmaf(ssc[k], s, c);
  }
}

// ----- phase3: Y = (L o C B^T) X + diag(exp(la)) C S_prev + D*x -----
__global__ __launch_bounds__(256, 3) void k_phase3(
    const float* __restrict__ dtbuf, const float* __restrict__ lac,
    const float* __restrict__ Bm, const float* __restrict__ Cm,
    const float* __restrict__ xs, const float* __restrict__ Sp,
    const float* __restrict__ Dparam, float* __restrict__ y){
  __shared__ __align__(16) float sBt[64][68];  // B^T [n][s] -> X [s][p]
  __shared__ __align__(16) float sCt[64][68];  // C^T [n][i]
  __shared__ __align__(16) float sSG[64][68];  // Sp [n][p] -> GM^T [s][i]
  __shared__ float sdt[64], sla[64];
  int tid = threadIdx.x, blk = blockIdx.x;
  int bh = blk>>6, k = blk&63, b = bh>>3, hh = bh&7, t0 = k*64;

  int rs = tid>>2, c0 = (tid&3)*12;
  float4 xpre0, xpre1, xpre2;
  {
    const float* xsrc = xs + (size_t)(bh*4096+t0+rs)*48 + c0;
    xpre0 = *(const float4*)(xsrc);
    xpre1 = *(const float4*)(xsrc+4);
    xpre2 = *(const float4*)(xsrc+8);
  }
  if (tid < 64){
    sdt[tid] = dtbuf[(size_t)bh*4096 + t0 + tid];
    sla[tid] = lac[(size_t)blk*64 + tid];
  }
  {
    const float* ssrc = Sp + (size_t)blk*3072 + rs*48 + c0;
    *(float4*)&sSG[rs][c0]   = *(const float4*)(ssrc);
    *(float4*)&sSG[rs][c0+4] = *(const float4*)(ssrc+4);
    *(float4*)&sSG[rs][c0+8] = *(const float4*)(ssrc+8);
  }
  {
    int s = tid>>2, n0 = (tid&3)*16;
    const float* bsrc = Bm + (size_t)(b*4096+t0+s)*64 + n0;
    const float* csrc = Cm + (size_t)(b*4096+t0+s)*64 + n0;
    #pragma unroll
    for (int q=0;q<4;q++){
      float4 bv = *(const float4*)(bsrc + q*4);
      float4 cv = *(const float4*)(csrc + q*4);
      sBt[n0+q*4+0][s]=bv.x; sBt[n0+q*4+1][s]=bv.y; sBt[n0+q*4+2][s]=bv.z; sBt[n0+q*4+3][s]=bv.w;
      sCt[n0+q*4+0][s]=cv.x; sCt[n0+q*4+1][s]=cv.y; sCt[n0+q*4+2][s]=cv.z; sCt[n0+q*4+3][s]=cv.w;
    }
  }
  __syncthreads();

  int i0p = (tid/12)*4, p0 = (tid%12)*4;
  float acc[4][4];
  #pragma unroll
  for (int i=0;i<4;i++)
    #pragma unroll
    for (int j=0;j<4;j++) acc[i][j]=0.f;
  if (tid < 192){
    #pragma unroll 4
    for (int n=0;n<64;n++){
      float cv[4], sp[4];
      *(float4*)cv = *(float4*)&sCt[n][i0p];
      *(float4*)sp = *(float4*)&sSG[n][p0];
      #pragma unroll
      for (int ii=0;ii<4;ii++)
        #pragma unroll
        for (int j=0;j<4;j++) acc[ii][j] = fmaf(cv[ii], sp[j], acc[ii][j]);
    }
  }
  int ig = (tid>>4)*4, sg = (tid&15)*4;
  float gm[4][4];
  #pragma unroll
  for (int i=0;i<4;i++)
    #pragma unroll
    for (int j=0;j<4;j++) gm[i][j]=0.f;
  if (sg <= ig+3){
    #pragma unroll 4
    for (int n=0;n<64;n++){
      float cv[4], bv[4];
      *(float4*)cv = *(float4*)&sCt[n][ig];
      *(float4*)bv = *(float4*)&sBt[n][sg];
      #pragma unroll
      for (int ii=0;ii<4;ii++)
        #pragma unroll
        for (int ss=0;ss<4;ss++) gm[ii][ss] = fmaf(cv[ii], bv[ss], gm[ii][ss]);
    }
    #pragma unroll
    for (int ii=0;ii<4;ii++)
      #pragma unroll
      for (int ss=0;ss<4;ss++){
        int i = ig+ii, s = sg+ss;
        gm[ii][ss] = (s<=i) ? gm[ii][ss]*__expf(sla[i]-sla[s])*sdt[s] : 0.f;
      }
  }
  __syncthreads();

  #pragma unroll
  for (int ss=0;ss<4;ss++){
    float4 o; o.x=gm[0][ss]; o.y=gm[1][ss]; o.z=gm[2][ss]; o.w=gm[3][ss];
    *(float4*)&sSG[sg+ss][ig] = o;
  }
  *(float4*)&sBt[rs][c0]   = xpre0;
  *(float4*)&sBt[rs][c0+4] = xpre1;
  *(float4*)&sBt[rs][c0+8] = xpre2;
  if (tid < 192){
    #pragma unroll
    for (int ii=0;ii<4;ii++){
      float ci = __expf(sla[i0p+ii]);
      #pragma unroll
      for (int j=0;j<4;j++) acc[ii][j] *= ci;
    }
  }
  __syncthreads();

  if (tid < 192){
    for (int s0=0; s0<=i0p; s0+=4){
      #pragma unroll
      for (int q=0;q<4;q++){
        float gv[4], xv[4];
        *(float4*)gv = *(float4*)&sSG[s0+q][i0p];
        *(float4*)xv = *(float4*)&sBt[s0+q][p0];
        #pragma unroll
        for (int ii=0;ii<4;ii++)
          #pragma unroll
          for (int j=0;j<4;j++) acc[ii][j] = fmaf(gv[ii], xv[j], acc[ii][j]);
      }
    }
    float Dh = Dparam[hh];
    #pragma unroll
    for (int ii=0;ii<4;ii++){
      int i = i0p+ii;
      float4 xd = *(float4*)&sBt[i][p0];
      float4 o;
      o.x = acc[ii][0] + Dh*xd.x;
      o.y = acc[ii][1] + Dh*xd.y;
      o.z = acc[ii][2] + Dh*xd.z;
      o.w = acc[ii][3] + Dh*xd.w;
      *(float4*)(y + (size_t)(b*4096+t0+i)*384 + hh*48 + p0) = o;
    }
  }
}

// ----- gate: z recomputed from x (K=4); g=y*silu(z); RMSNorm; write yn -----
__global__ __launch_bounds__(384) void k_gate(
    const float* __restrict__ x, const float* __restrict__ Weff,
    const float* __restrict__ beff, const float* __restrict__ norm_w,
    const float* __restrict__ y, float* __restrict__ yn){
  __shared__ float sred[6];
  __shared__ float srms;
  __shared__ float sx[4];
  int bl = blockIdx.x, tid = threadIdx.x;
  if (tid < 4) sx[tid] = x[(size_t)bl*4 + tid];
  __syncthreads();
  float zv = beff[tid];
  zv = fmaf(sx[0], Weff[tid], zv);
  zv = fmaf(sx[1], Weff[904+tid], zv);
  zv = fmaf(sx[2], Weff[1808+tid], zv);
  zv = fmaf(sx[3], Weff[2712+tid], zv);
  float yv = y[(size_t)bl*384 + tid];
  float g = yv * (zv * sigmoidf_(zv));
  float ss = g*g;
  #pragma unroll
  for (int off=32; off>0; off>>=1) ss += __shfl_xor(ss, off);
  if ((tid&63)==0) sred[tid>>6] = ss;
  __syncthreads();
  if (tid==0){
    float t=0.f;
    #pragma unroll
    for (int i=0;i<6;i++) t += sred[i];
    srms = rsqrtf(t*(1.f/384.f) + 1e-5f);
  }
  __syncthreads();
  yn[(size_t)bl*384 + tid] = g * srms * norm_w[tid];
}

// ----- mlp2: m1 = relu(yn@Weff2 + b1) [K=384], m2 = relu(m1@W2+b2), mean -----
__global__ __launch_bounds__(256) void k_mlp2(
    const float* __restrict__ yn, const float* __restrict__ Weff2,
    const float* __restrict__ b1, const float* __restrict__ W2,
    const float* __restrict__ b2, float* __restrict__ macc){
  __shared__ __align__(16) float sW[384][32];   // 48 KB
  __shared__ __align__(16) float sm1[32][33];
  __shared__ __align__(16) float sW2[32][32];
  __shared__ __align__(16) float sm2[32][33];
  int tid = threadIdx.x;
  int tok0 = blockIdx.x*32;
  int b = tok0 >> 12;
  #pragma unroll
  for (int r=0;r<12;r++){
    int idx = tid + r*256;                 // float4 index over 3072
    int row = idx>>3, c4 = (idx&7)*4;
    *(float4*)&sW[row][c4] = *(const float4*)(Weff2 + (size_t)idx*4);
  }
  {
    int row = tid>>3, c4 = (tid&7)*4;
    *(float4*)&sW2[row][c4] = *(const float4*)(W2 + row*32 + c4);
  }
  __syncthreads();
  {
    int tok = tid>>3, j0 = (tid&7)*4;
    float a0[4];
    #pragma unroll
    for (int j=0;j<4;j++) a0[j] = b1[j0+j];
    const float* yrow = yn + (size_t)(tok0+tok)*384;
    for (int k4=0;k4<96;k4++){
      float4 a = *(const float4*)(yrow + k4*4);
      float w[4];
      *(float4*)w = *(float4*)&sW[k4*4+0][j0];
      #pragma unroll
      for (int j=0;j<4;j++) a0[j] = fmaf(a.x, w[j], a0[j]);
      *(float4*)w = *(float4*)&sW[k4*4+1][j0];
      #pragma unroll
      for (int j=0;j<4;j++) a0[j] = fmaf(a.y, w[j], a0[j]);
      *(float4*)w = *(float4*)&sW[k4*4+2][j0];
      #pragma unroll
      for (int j=0;j<4;j++) a0[j] = fmaf(a.z, w[j], a0[j]);
      *(float4*)w = *(float4*)&sW[k4*4+3][j0];
      #pragma unroll
      for (int j=0;j<4;j++) a0[j] = fmaf(a.w, w[j], a0[j]);
    }
    #pragma unroll
    for (int j=0;j<4;j++) sm1[tok][j0+j] = fmaxf(a0[j], 0.f);
  }
  __syncthreads();
  {
    int tok = tid>>3, j0 = (tid&7)*4;
    float a0[4];
    #pragma unroll
    for (int j=0;j<4;j++) a0[j] = b2[j0+j];
    #pragma unroll
    for (int kk=0;kk<32;kk++){
      float a = sm1[tok][kk];
      float w[4]; *(float4*)w = *(float4*)&sW2[kk][j0];
      #pragma unroll
      for (int j=0;j<4;j++) a0[j] = fmaf(a, w[j], a0[j]);
    }
    #pragma unroll
    for (int j=0;j<4;j++) sm2[tok][j0+j] = fmaxf(a0[j], 0.f);
  }
  __syncthreads();
  if (tid < 32){
    float t = 0.f;
    #pragma unroll
    for (int tok=0;tok<32;tok++) t += sm2[tok][tid];
    atomicAdd(&macc[b*32 + tid], t);
  }
}

// ----- final: angle[b] = mean_m @ Wo + bo -----
__global__ void k_final(const float* __restrict__ macc, const float* __restrict__ Wo,
                        const float* __restrict__ bo, float* __restrict__ out){
  int tid = threadIdx.x;
  if (tid < 4){
    float acc = bo[0];
    #pragma unroll
    for (int j=0;j<32;j++) acc = fmaf(macc[tid*32+j]*(1.f/4096.f), Wo[j], acc);
    out[tid] = acc;
  }
}

// ---------------------------------------------------------------------------
extern "C" void kernel_launch(void* const* d_in, const int* in_sizes, int n_in,
                              void* d_out, int out_size, void* d_ws, size_t ws_size,
                              hipStream_t stream){
  const float* x      = (const float*)d_in[0];
  const float* Wfc    = (const float*)d_in[1];
  const float* bfc    = (const float*)d_in[2];
  const float* W_in   = (const float*)d_in[3];
  const float* conv_w = (const float*)d_in[4];
  const float* conv_b = (const float*)d_in[5];
  const float* dt_bias= (const float*)d_in[6];
  const float* A_log  = (const float*)d_in[7];
  const float* Dparam = (const float*)d_in[8];
  const float* norm_w = (const float*)d_in[9];
  const float* W_out  = (const float*)d_in[10];
  const float* W1     = (const float*)d_in[11];
  const float* b1     = (const float*)d_in[12];
  const float* W2     = (const float*)d_in[13];
  const float* b2     = (const float*)d_in[14];
  const float* Wo     = (const float*)d_in[15];
  const float* bo     = (const float*)d_in[16];
  float* ws  = (float*)d_ws;
  float* out = (float*)d_out;

  float* Weff  = ws + OFF_W;          // 4x904
  float* beff  = ws + OFF_W + 4096;   // 904
  float* Weff2 = ws + OFF_W + 8192;   // 384x32
  float* yn    = ws + OFF_Z;
  float* Tb    = ws + OFF_T;
  float* xsb   = ws + OFF_XS;
  float* Bmb   = ws + OFF_BM;
  float* Cmb   = ws + OFF_CM;
  float* dtb   = ws + OFF_DT;
  float* lacb  = ws + OFF_LAC;
  float* Spb   = ws + OFF_SP;
  float* yb    = ws + OFF_Y;
  float* macc  = ws + OFF_MACC;

  hipMemsetAsync((void*)macc, 0, 128*sizeof(float), stream);

  k_prep1<<<dim3(4), dim3(256), 0, stream>>>(Wfc, bfc, W_in, Weff, beff);
  k_prep2<<<dim3(48), dim3(256), 0, stream>>>(W_out, W1, Weff2);
  k_ipc<<<dim3(BL), dim3(256), 0, stream>>>(x, Weff, beff, conv_w, conv_b,
                                            dt_bias, xsb, Bmb, Cmb, dtb);
  k_phase1<<<dim3(BH*NC), dim3(256), 0, stream>>>(dtb, Bmb, xsb, A_log, Tb, lacb);
  k_phase2<<<dim3(BH,8), dim3(384), 0, stream>>>(Tb, lacb, Spb);
  k_phase3<<<dim3(BH*NC), dim3(256), 0, stream>>>(dtb, lacb, Bmb, Cmb, xsb, Spb, Dparam, yb);
  k_gate<<<dim3(BL), dim3(384), 0, stream>>>(x, Weff, beff, norm_w, yb, yn);
  k_mlp2<<<dim3(BL/32), dim3(256), 0, stream>>>(yn, Weff2, b1, W2, b2, macc);
  k_final<<<dim3(1), dim3(64), 0, stream>>>(macc, Wo, bo, out);
}